// Round 2
// baseline (1085.624 us; speedup 1.0000x reference)
//
#include <hip/hip_runtime.h>
#include <math.h>

// ---------------------------------------------------------------------------
// MultiheadAttention fwd, MI355X. B=8 N=1024 E=768 H=12 D=64.
//   K0 split_convert : X, Wq/k/v/o fp32 -> (hi,lo) bf16 pairs in ws
//   K1 qkv_gemm      : split-bf16 MFMA (3-pass hi/lo), out [B,H,N,D], q*=1/8
//   K2 attn_kernel   : fp32 flash-style online-softmax (unchanged, trusted)
//   K2b split_attn   : attn fp32 -> (hi,lo) bf16
//   K3 out_gemm      : split-bf16 MFMA, out = attn@Wo.T + bo
// Split-bf16: x*w ~= xh*wh + xh*wl + xl*wh, error ~1e-4 rel over K=768.
// ---------------------------------------------------------------------------

namespace {

constexpr int kB = 8, kN = 1024, kE = 768, kH = 12, kD = 64;
constexpr int kM = kB * kN;          // 8192 rows
constexpr int kNX = kM * kE;         // 6,291,456 elems of X (also attn)
constexpr int kNW = kE * kE;         // 589,824 elems per weight
constexpr int kTot = kNX + 4 * kNW;  // 8,650,752

typedef short bf16x8 __attribute__((ext_vector_type(8)));
typedef float f32x4 __attribute__((ext_vector_type(4)));

__device__ __forceinline__ ushort f2bf(float x) {
  uint u = __float_as_uint(x);
  u += 0x7fffu + ((u >> 16) & 1u);  // RNE
  return (ushort)(u >> 16);
}
__device__ __forceinline__ float bf2f(ushort h) {
  return __uint_as_float(((uint)h) << 16);
}

// ---------------- K0: fp32 -> (hi, lo) bf16 split (X + 4 weights) ----------
__global__ __launch_bounds__(256)
void split_convert(const float* __restrict__ X, const float* __restrict__ Wq,
                   const float* __restrict__ Wk, const float* __restrict__ Wv,
                   const float* __restrict__ Wo, ushort* __restrict__ Xh,
                   ushort* __restrict__ Xl, ushort* __restrict__ Wh,
                   ushort* __restrict__ Wl) {
  const int gid = blockIdx.x * 256 + threadIdx.x;
  const int i4 = gid * 4;
  if (i4 >= kTot) return;
  const float* s;
  ushort *dh, *dl;
  if (i4 < kNX) {
    s = X + i4;
    dh = Xh + i4;
    dl = Xl + i4;
  } else {
    const int j = i4 - kNX;
    const int w = j / kNW;
    const int o = j - w * kNW;
    s = (w == 0) ? Wq + o : (w == 1) ? Wk + o : (w == 2) ? Wv + o : Wo + o;
    dh = Wh + j;
    dl = Wl + j;
  }
  const float4 v = *(const float4*)s;
  ushort4 h, l;
  h.x = f2bf(v.x);
  h.y = f2bf(v.y);
  h.z = f2bf(v.z);
  h.w = f2bf(v.w);
  l.x = f2bf(v.x - bf2f(h.x));
  l.y = f2bf(v.y - bf2f(h.y));
  l.z = f2bf(v.z - bf2f(h.z));
  l.w = f2bf(v.w - bf2f(h.w));
  *(ushort4*)dh = h;
  *(ushort4*)dl = l;
}

// ---------------- K2b: fp32 -> (hi, lo) bf16 split (attn only) -------------
__global__ __launch_bounds__(256)
void split_attn(const float* __restrict__ A, ushort* __restrict__ Ah,
                ushort* __restrict__ Al) {
  const int i4 = (blockIdx.x * 256 + threadIdx.x) * 4;
  if (i4 >= kNX) return;
  const float4 v = *(const float4*)(A + i4);
  ushort4 h, l;
  h.x = f2bf(v.x);
  h.y = f2bf(v.y);
  h.z = f2bf(v.z);
  h.w = f2bf(v.w);
  l.x = f2bf(v.x - bf2f(h.x));
  l.y = f2bf(v.y - bf2f(h.y));
  l.z = f2bf(v.z - bf2f(h.z));
  l.w = f2bf(v.w - bf2f(h.w));
  *(ushort4*)(Ah + i4) = h;
  *(ushort4*)(Al + i4) = l;
}

// ---------------- shared MFMA GEMM core ------------------------------------
// C(128x128) = A(128xK) . B(NxK)^T tile, split-bf16 3-pass.
// 4 waves (2x2), wave tile 64x64 = 4x4 frags of mfma_f32_16x16x32_bf16.
// Layouts (m89/m92-verified): A/B lane: row|col = lane&15, k = (lane>>4)*8+e;
// D: col = lane&15, row = (lane>>4)*4 + reg.
// LDS pitch 40 bf16 (80 B): frag b128 reads hit slot (5*row+g)%8 (conflict-free).
struct Frag44 {
  f32x4 a[4][4];
};

template <typename EPI>
__device__ __forceinline__ void gemm_core(const ushort* __restrict__ Ahg,
                                          const ushort* __restrict__ Alg,
                                          const ushort* __restrict__ Bhg,
                                          const ushort* __restrict__ Blg,
                                          int m0, int o0, EPI epi) {
  __shared__ ushort Ah[128][40], Al[128][40], Bh[128][40], Bl[128][40];
  const int tid = threadIdx.x;
  const int wid = tid >> 6, lane = tid & 63;
  const int wm = wid >> 1, wn = wid & 1;
  const int g = lane >> 4, lr = lane & 15;

  f32x4 acc[4][4];
#pragma unroll
  for (int i = 0; i < 4; ++i)
#pragma unroll
    for (int j = 0; j < 4; ++j) acc[i][j] = (f32x4)0.f;

  for (int k0 = 0; k0 < kE; k0 += 32) {
#pragma unroll
    for (int p = 0; p < 4; ++p) {
      const int f = tid + p * 256;
      const int m = f >> 3, kq = f & 7;
      const int ga = (m0 + m) * kE + k0 + kq * 4;
      const int gb = (o0 + m) * kE + k0 + kq * 4;
      *(uint2*)&Ah[m][kq * 4] = *(const uint2*)&Ahg[ga];
      *(uint2*)&Al[m][kq * 4] = *(const uint2*)&Alg[ga];
      *(uint2*)&Bh[m][kq * 4] = *(const uint2*)&Bhg[gb];
      *(uint2*)&Bl[m][kq * 4] = *(const uint2*)&Blg[gb];
    }
    __syncthreads();

    bf16x8 ah[4], al[4];
#pragma unroll
    for (int mi = 0; mi < 4; ++mi) {
      const int ar = wm * 64 + mi * 16 + lr;
      ah[mi] = *reinterpret_cast<const bf16x8*>(&Ah[ar][g * 8]);
      al[mi] = *reinterpret_cast<const bf16x8*>(&Al[ar][g * 8]);
    }
#pragma unroll
    for (int nj = 0; nj < 4; ++nj) {
      const int br = wn * 64 + nj * 16 + lr;
      const bf16x8 bh = *reinterpret_cast<const bf16x8*>(&Bh[br][g * 8]);
      const bf16x8 bl = *reinterpret_cast<const bf16x8*>(&Bl[br][g * 8]);
#pragma unroll
      for (int mi = 0; mi < 4; ++mi) {
        acc[mi][nj] = __builtin_amdgcn_mfma_f32_16x16x32_bf16(ah[mi], bh,
                                                              acc[mi][nj], 0, 0, 0);
        acc[mi][nj] = __builtin_amdgcn_mfma_f32_16x16x32_bf16(ah[mi], bl,
                                                              acc[mi][nj], 0, 0, 0);
        acc[mi][nj] = __builtin_amdgcn_mfma_f32_16x16x32_bf16(al[mi], bh,
                                                              acc[mi][nj], 0, 0, 0);
      }
    }
    __syncthreads();
  }

  // hand accumulators to the epilogue with global coords
#pragma unroll
  for (int nj = 0; nj < 4; ++nj) {
    const int o = o0 + wn * 64 + nj * 16 + lr;
#pragma unroll
    for (int mi = 0; mi < 4; ++mi) {
      const int mbase = m0 + wm * 64 + mi * 16 + g * 4;
#pragma unroll
      for (int r = 0; r < 4; ++r) epi(mbase + r, o, acc[mi][nj][r]);
    }
  }
}

// ---------------- K1: fused QKV projection ---------------------------------
__global__ __launch_bounds__(256)
void qkv_gemm(const ushort* __restrict__ Xh, const ushort* __restrict__ Xl,
              const ushort* __restrict__ Wh, const ushort* __restrict__ Wl,
              const float* __restrict__ bq, const float* __restrict__ bk,
              const float* __restrict__ bv, float* __restrict__ Qo,
              float* __restrict__ Ko, float* __restrict__ Vo) {
  const int z = blockIdx.z;
  const ushort* WhZ = Wh + (size_t)z * kNW;
  const ushort* WlZ = Wl + (size_t)z * kNW;
  const float* bb = (z == 0) ? bq : (z == 1) ? bk : bv;
  float* Y = (z == 0) ? Qo : (z == 1) ? Ko : Vo;
  const float scale = (z == 0) ? 0.125f : 1.0f;  // d^-0.5

  gemm_core(Xh, Xl, WhZ, WlZ, blockIdx.x * 128, blockIdx.y * 128,
            [=](int m, int o, float v) {
              const int bi = m >> 10, n = m & 1023;
              const int h = o >> 6, d = o & 63;
              Y[(((size_t)bi * kH + h) * kN + n) * kD + d] = (v + bb[o]) * scale;
            });
}

// ---------------- K3: output projection ------------------------------------
__global__ __launch_bounds__(256)
void out_gemm(const ushort* __restrict__ Ahg, const ushort* __restrict__ Alg,
              const ushort* __restrict__ Wh, const ushort* __restrict__ Wl,
              const float* __restrict__ bo, float* __restrict__ Y) {
  gemm_core(Ahg, Alg, Wh, Wl, blockIdx.x * 128, blockIdx.y * 128,
            [=](int m, int o, float v) { Y[(size_t)m * kE + o] = v + bo[o]; });
}

// ---------------- K2: attention (fp32 flash-style, fused bias) -------------
__global__ __launch_bounds__(256)
void attn_kernel(const float* __restrict__ Q, const float* __restrict__ K,
                 const float* __restrict__ V, const float* __restrict__ bias,
                 float* __restrict__ Ao) {
  __shared__ float Qs[64][64];   // [d][i]
  __shared__ float Ks[64][64];   // [d][j]
  __shared__ float Vs[64][64];   // [j][d]
  __shared__ float St[64][65];   // [j][i]
  __shared__ float red[4][64];
  __shared__ float mrow[64], lrow[64], srow[64];

  const int n0 = blockIdx.x * 64;
  const int h = blockIdx.y, b = blockIdx.z;
  const int tid = threadIdx.x;
  const int ty = tid >> 4, tx = tid & 15;
  const int i0 = ty * 4, j0 = tx * 4, d0 = tx * 4;
  const int irow = tid & 63, qtr = tid >> 6;

  const size_t headoff = ((size_t)(b * kH + h)) * kN * kD;
  const float* __restrict__ Qh = Q + headoff;
  const float* __restrict__ Kh = K + headoff;
  const float* __restrict__ Vh = V + headoff;
  const float* __restrict__ biash = bias + ((size_t)(b * kH + h)) * kN * kN;

#pragma unroll
  for (int p = 0; p < 4; ++p) {
    const int r = (tid >> 4) + p * 16;
    const int dq = (tid & 15) * 4;
    const float4 v4 = *(const float4*)&Qh[(size_t)(n0 + r) * kD + dq];
    Qs[dq + 0][r] = v4.x;
    Qs[dq + 1][r] = v4.y;
    Qs[dq + 2][r] = v4.z;
    Qs[dq + 3][r] = v4.w;
  }
  if (tid < 64) {
    mrow[tid] = -__builtin_inff();
    lrow[tid] = 0.f;
  }
  float O[4][4];
#pragma unroll
  for (int i = 0; i < 4; ++i)
#pragma unroll
    for (int j = 0; j < 4; ++j) O[i][j] = 0.f;
  __syncthreads();

  for (int t = 0; t < 16; ++t) {
    const int jg = t * 64;
#pragma unroll
    for (int p = 0; p < 4; ++p) {
      const int r = (tid >> 4) + p * 16;
      const int dq = (tid & 15) * 4;
      const float4 kv = *(const float4*)&Kh[(size_t)(jg + r) * kD + dq];
      Ks[dq + 0][r] = kv.x;
      Ks[dq + 1][r] = kv.y;
      Ks[dq + 2][r] = kv.z;
      Ks[dq + 3][r] = kv.w;
      *(float4*)&Vs[r][dq] = *(const float4*)&Vh[(size_t)(jg + r) * kD + dq];
    }
    __syncthreads();  // B1

    float s[4][4];
#pragma unroll
    for (int i = 0; i < 4; ++i)
#pragma unroll
      for (int j = 0; j < 4; ++j) s[i][j] = 0.f;
    for (int d = 0; d < 64; ++d) {
      float a[4], kb[4];
      *(float4*)&a[0] = *(const float4*)&Qs[d][i0];
      *(float4*)&kb[0] = *(const float4*)&Ks[d][j0];
#pragma unroll
      for (int i = 0; i < 4; ++i)
#pragma unroll
        for (int j = 0; j < 4; ++j) s[i][j] = fmaf(a[i], kb[j], s[i][j]);
    }
#pragma unroll
    for (int i = 0; i < 4; ++i) {
      const float4 bv4 =
          *(const float4*)&biash[(size_t)(n0 + i0 + i) * kN + jg + j0];
      St[j0 + 0][i0 + i] = s[i][0] + bv4.x;
      St[j0 + 1][i0 + i] = s[i][1] + bv4.y;
      St[j0 + 2][i0 + i] = s[i][2] + bv4.z;
      St[j0 + 3][i0 + i] = s[i][3] + bv4.w;
    }
    __syncthreads();  // B2

    float pm = -__builtin_inff();
#pragma unroll
    for (int j = 0; j < 16; ++j) pm = fmaxf(pm, St[qtr * 16 + j][irow]);
    red[qtr][irow] = pm;
    __syncthreads();  // B3
    if (tid < 64) {
      const float tm = fmaxf(fmaxf(red[0][tid], red[1][tid]),
                             fmaxf(red[2][tid], red[3][tid]));
      const float mo = mrow[tid];
      const float mn = fmaxf(mo, tm);
      mrow[tid] = mn;
      srow[tid] = __expf(mo - mn);
    }
    __syncthreads();  // B4

    const float mi = mrow[irow];
    float ps = 0.f;
#pragma unroll
    for (int j = 0; j < 16; ++j) {
      const float e = __expf(St[qtr * 16 + j][irow] - mi);
      St[qtr * 16 + j][irow] = e;
      ps += e;
    }
    red[qtr][irow] = ps;
    __syncthreads();  // B5
    if (tid < 64)
      lrow[tid] = lrow[tid] * srow[tid] +
                  (red[0][tid] + red[1][tid] + red[2][tid] + red[3][tid]);

    float sf[4];
#pragma unroll
    for (int i = 0; i < 4; ++i) sf[i] = srow[i0 + i];
#pragma unroll
    for (int i = 0; i < 4; ++i)
#pragma unroll
      for (int j = 0; j < 4; ++j) O[i][j] *= sf[i];
#pragma unroll 8
    for (int j = 0; j < 64; ++j) {
      const float4 vv = *(const float4*)&Vs[j][d0];
      const float p0 = St[j][i0 + 0];
      const float p1 = St[j][i0 + 1];
      const float p2 = St[j][i0 + 2];
      const float p3 = St[j][i0 + 3];
      O[0][0] = fmaf(p0, vv.x, O[0][0]);
      O[0][1] = fmaf(p0, vv.y, O[0][1]);
      O[0][2] = fmaf(p0, vv.z, O[0][2]);
      O[0][3] = fmaf(p0, vv.w, O[0][3]);
      O[1][0] = fmaf(p1, vv.x, O[1][0]);
      O[1][1] = fmaf(p1, vv.y, O[1][1]);
      O[1][2] = fmaf(p1, vv.z, O[1][2]);
      O[1][3] = fmaf(p1, vv.w, O[1][3]);
      O[2][0] = fmaf(p2, vv.x, O[2][0]);
      O[2][1] = fmaf(p2, vv.y, O[2][1]);
      O[2][2] = fmaf(p2, vv.z, O[2][2]);
      O[2][3] = fmaf(p2, vv.w, O[2][3]);
      O[3][0] = fmaf(p3, vv.x, O[3][0]);
      O[3][1] = fmaf(p3, vv.y, O[3][1]);
      O[3][2] = fmaf(p3, vv.z, O[3][2]);
      O[3][3] = fmaf(p3, vv.w, O[3][3]);
    }
    __syncthreads();  // B6
  }

#pragma unroll
  for (int i = 0; i < 4; ++i) {
    const float inv = 1.0f / lrow[i0 + i];
    float4 r;
    r.x = O[i][0] * inv;
    r.y = O[i][1] * inv;
    r.z = O[i][2] * inv;
    r.w = O[i][3] * inv;
    *(float4*)&Ao[((size_t)b * kN + n0 + i0 + i) * kE + h * kD + d0] = r;
  }
}

}  // namespace

// ---------------------------------------------------------------------------
extern "C" void kernel_launch(void* const* d_in, const int* in_sizes, int n_in,
                              void* d_out, int out_size, void* d_ws,
                              size_t ws_size, hipStream_t stream) {
  (void)in_sizes;
  (void)n_in;
  (void)out_size;
  (void)ws_size;
  const float* x = (const float*)d_in[0];
  const float* bias = (const float*)d_in[1];
  const float* Wq = (const float*)d_in[2];
  const float* bq = (const float*)d_in[3];
  const float* Wk = (const float*)d_in[4];
  const float* bk = (const float*)d_in[5];
  const float* Wv = (const float*)d_in[6];
  const float* bv = (const float*)d_in[7];
  const float* Wo = (const float*)d_in[8];
  const float* bo = (const float*)d_in[9];
  float* out = (float*)d_out;

  // ws: q,k,v [B,H,N,D] + attn [B,N,E] fp32; then bf16 hi/lo splits.
  const size_t per = (size_t)kB * kH * kN * kD;  // 6,291,456
  float* q = (float*)d_ws;
  float* k = q + per;
  float* v = k + per;
  float* attn = v + per;
  ushort* Xh = (ushort*)(attn + per);
  ushort* Xl = Xh + kNX;
  ushort* Whs = Xl + kNX;  // [4][kNW], order q,k,v,o
  ushort* Wls = Whs + 4 * (size_t)kNW;
  ushort* AttnH = Wls + 4 * (size_t)kNW;
  ushort* AttnL = AttnH + kNX;
  // total = 100.7 + 34.6 + 25.2 = 160.5 MB

  split_convert<<<kTot / 1024, 256, 0, stream>>>(x, Wq, Wk, Wv, Wo, Xh, Xl,
                                                 Whs, Wls);

  dim3 g1(kM / 128, kE / 128, 3);
  qkv_gemm<<<g1, 256, 0, stream>>>(Xh, Xl, Whs, Wls, bq, bk, bv, q, k, v);

  dim3 g2(kN / 64, kH, kB);
  attn_kernel<<<g2, 256, 0, stream>>>(q, k, v, bias, attn);

  split_attn<<<kNX / 1024, 256, 0, stream>>>(attn, AttnH, AttnL);

  dim3 g3(kM / 128, kE / 128);
  out_gemm<<<g3, 256, 0, stream>>>(AttnH, AttnL, Whs + 3 * (size_t)kNW,
                                   Wls + 3 * (size_t)kNW, bo, out);
}